// Round 1
// baseline (1014.235 us; speedup 1.0000x reference)
//
#include <hip/hip_runtime.h>
#include <cstdint>
#include <cfloat>

#define N_   32
#define D_   512
#define T_   2048
#define NC   512
#define NROW (N_ * T_)           // 65536 rows
#define OUT_ELEMS (N_ * D_ * T_) // 33554432
#define KT   32                  // K tile (d per stage)
#define TTB  64                  // t columns per block
#define THREADS 512
#define DELTA 1e-4f

// ws layout (4-byte units):
// [0]        commit-loss accumulator (float)
// [1..512]   histogram (uint32)
// [520..1031] cbn2 (float)

__global__ void zero_ws(float* ws) {
    int i = threadIdx.x;
    if (i < 520) ws[i] = 0.0f;
}

__global__ __launch_bounds__(256) void cbnorm_k(const float* __restrict__ cb,
                                                float* __restrict__ cbn2) {
    int w = threadIdx.x >> 6, lane = threadIdx.x & 63;
    int c = blockIdx.x * 4 + w;
    const float4* row = (const float4*)(cb + (size_t)c * D_);
    float4 a = row[lane * 2], b = row[lane * 2 + 1];
    float s = a.x*a.x + a.y*a.y + a.z*a.z + a.w*a.w
            + b.x*b.x + b.y*b.y + b.z*b.z + b.w*b.w;
    for (int o = 32; o; o >>= 1) s += __shfl_down(s, o);
    if (lane == 0) cbn2[c] = s;
}

__global__ __launch_bounds__(THREADS) void vq_main(
    const float* __restrict__ x, const float* __restrict__ cb,
    float* __restrict__ out, float* __restrict__ closs,
    unsigned int* __restrict__ hist, const float* __restrict__ cbn2g) {

    __shared__ union U {
        float cbt[KT][NC + 4];   // 66048 B, k-slab of codebook, transposed [d][c]
        struct {
            float redv[TTB][65];
            int   redi[TTB][65];
            float ot[64][TTB + 1];
        } ep;
    } u;
    __shared__ float xs[KT][TTB];      // x k-slab [d][t]
    __shared__ float xn2p[8][TTB];
    __shared__ float scl[TTB];
    __shared__ float cbn2s[NC];
    __shared__ float m1s[TTB];
    __shared__ int   sidx[TTB];
    __shared__ int   ccnt[TTB];
    __shared__ int   cand[TTB][8];
    __shared__ float clw[8];

    const int tid = threadIdx.x;
    const int bid = blockIdx.x;
    const int n   = bid >> 5;              // 32 blocks per n
    const int t0  = (bid & 31) * TTB;
    const size_t xbase = (size_t)n * D_ * T_ + t0;

    cbn2s[tid] = cbn2g[tid];               // 512 threads -> 512 values

    const int ct = tid >> 3, tg = tid & 7;
    const int c0 = ct * 8, tt0 = tg * 8;
    const int tN = tid & 63, dcN = tid >> 6;

    float acc[8][8];
#pragma unroll
    for (int i = 0; i < 8; ++i)
#pragma unroll
        for (int j = 0; j < 8; ++j) acc[i][j] = 0.f;

    float xn2part = 0.f;

    for (int kt = 0; kt < D_ / KT; ++kt) {
        // stage x tile: coalesced along t
#pragma unroll
        for (int it = 0; it < 4; ++it) {
            int f = it * THREADS + tid;
            int dd = f >> 6, tt = f & 63;
            xs[dd][tt] = x[xbase + (size_t)(kt * KT + dd) * T_ + tt];
        }
        // stage codebook slab transposed: coalesced along d
#pragma unroll
        for (int it = 0; it < 32; ++it) {
            int f = it * THREADS + tid;
            int c = f >> 5, dd = f & 31;
            u.cbt[dd][c] = cb[(size_t)c * D_ + kt * KT + dd];
        }
        __syncthreads();
        // row-norm partials (wave dcN handles d rows dcN*4..+3)
#pragma unroll
        for (int r = 0; r < 4; ++r) {
            float v = xs[dcN * 4 + r][tN];
            xn2part += v * v;
        }
        // 8x8 register-tile FMA over this k-slab
#pragma unroll
        for (int dd = 0; dd < KT; ++dd) {
            float4 a0 = *(const float4*)&u.cbt[dd][c0];
            float4 a1 = *(const float4*)&u.cbt[dd][c0 + 4];
            float4 b0 = *(const float4*)&xs[dd][tt0];
            float4 b1 = *(const float4*)&xs[dd][tt0 + 4];
            float av[8] = {a0.x, a0.y, a0.z, a0.w, a1.x, a1.y, a1.z, a1.w};
            float bv[8] = {b0.x, b0.y, b0.z, b0.w, b1.x, b1.y, b1.z, b1.w};
#pragma unroll
            for (int i = 0; i < 8; ++i)
#pragma unroll
                for (int j = 0; j < 8; ++j)
                    acc[i][j] = fmaf(av[i], bv[j], acc[i][j]);
        }
        __syncthreads();
    }

    // finish row norms -> scale
    xn2p[dcN][tN] = xn2part;
    __syncthreads();
    if (tid < TTB) {
        float s = 0.f;
#pragma unroll
        for (int r = 0; r < 8; ++r) s += xn2p[r][tid];
        scl[tid] = 1.0f / fmaxf(sqrtf(s), 1e-12f);
        ccnt[tid] = 0;
    }
    __syncthreads();

    // per-thread argmin over its 8 codes, per t column
#pragma unroll
    for (int j = 0; j < 8; ++j) {
        int tt = tt0 + j;
        float sc2 = 2.0f * scl[tt];
        float bv = FLT_MAX; int bi = 0;
#pragma unroll
        for (int i = 0; i < 8; ++i) {
            float v = cbn2s[c0 + i] - sc2 * acc[i][j];
            if (v < bv) { bv = v; bi = c0 + i; }
        }
        u.ep.redv[tt][ct] = bv;
        u.ep.redi[tt][ct] = bi;
    }
    __syncthreads();
    if (tid < TTB) {
        float bv = FLT_MAX; int bi = 0;
        for (int c = 0; c < 64; ++c) {        // ascending ct -> first-index tiebreak
            float v = u.ep.redv[tid][c];
            if (v < bv) { bv = v; bi = u.ep.redi[tid][c]; }
        }
        m1s[tid]  = bv;
        sidx[tid] = bi;
    }
    __syncthreads();

    // collect near-tie candidates (within DELTA of fp32 min)
#pragma unroll
    for (int j = 0; j < 8; ++j) {
        int tt = tt0 + j;
        float sc2 = 2.0f * scl[tt];
        float thr = m1s[tt] + DELTA;
#pragma unroll
        for (int i = 0; i < 8; ++i) {
            float v = cbn2s[c0 + i] - sc2 * acc[i][j];
            if (v <= thr) {
                int pos = atomicAdd(&ccnt[tt], 1);
                if (pos < 8) cand[tt][pos] = c0 + i;
            }
        }
    }
    __syncthreads();

    // fp64 refinement for ambiguous rows; then histogram
    if (tid < TTB) {
        int cnt = ccnt[tid];
        if (cnt > 1) {
            int m = cnt < 8 ? cnt : 8;
            const float* xr = x + xbase + tid;
            double xn2d = 0.0;
            for (int d = 0; d < D_; ++d) { double v = (double)xr[(size_t)d * T_]; xn2d += v * v; }
            double nrm = sqrt(xn2d); if (nrm < 1e-12) nrm = 1e-12;
            double inv = 1.0 / nrm;
            double bd = 1e300; int bc = 1 << 30;
            for (int k = 0; k < m; ++k) {
                int c = cand[tid][k];
                const float* cr = cb + (size_t)c * D_;
                double s = 0.0;
                for (int d = 0; d < D_; ++d) {
                    double df = (double)xr[(size_t)d * T_] * inv - (double)cr[d];
                    s += df * df;
                }
                if (s < bd || (s == bd && c < bc)) { bd = s; bc = c; }
            }
            sidx[tid] = bc;
        }
        atomicAdd(&hist[sidx[tid]], 1u);
    }
    __syncthreads();

    // epilogue: gather chosen codebook rows via LDS, coalesced out write + commit loss
    float cl = 0.f;
    for (int dc8 = 0; dc8 < 8; ++dc8) {
        int dbase = dc8 * 64;
        {
            int tt = tid >> 3, jj = tid & 7;
            int c = sidx[tt];
            const float4* src = (const float4*)(cb + (size_t)c * D_ + dbase + jj * 8);
            float4 p0 = src[0], p1 = src[1];
            int dd = jj * 8;
            u.ep.ot[dd + 0][tt] = p0.x; u.ep.ot[dd + 1][tt] = p0.y;
            u.ep.ot[dd + 2][tt] = p0.z; u.ep.ot[dd + 3][tt] = p0.w;
            u.ep.ot[dd + 4][tt] = p1.x; u.ep.ot[dd + 5][tt] = p1.y;
            u.ep.ot[dd + 6][tt] = p1.z; u.ep.ot[dd + 7][tt] = p1.w;
        }
        __syncthreads();
#pragma unroll
        for (int i = 0; i < 8; ++i) {
            int e = i * THREADS + tid;
            int dd = e >> 6, tt = e & 63;
            size_t g = xbase + (size_t)(dbase + dd) * T_ + tt;
            float xv = x[g] * scl[tt];
            float od = u.ep.ot[dd][tt];
            out[g] = xv + (od - xv);          // STE: numerically x_d
            float df = xv - od;
            cl = fmaf(df, df, cl);
        }
        __syncthreads();
    }

    for (int o = 32; o; o >>= 1) cl += __shfl_down(cl, o);
    if ((tid & 63) == 0) clw[tid >> 6] = cl;
    __syncthreads();
    if (tid == 0) {
        float s = 0.f;
#pragma unroll
        for (int w = 0; w < 8; ++w) s += clw[w];
        atomicAdd(closs, s);
    }
}

__global__ __launch_bounds__(512) void finalize_k(const unsigned int* __restrict__ hist,
                                                  const float* __restrict__ closs,
                                                  float* __restrict__ out) {
    __shared__ float ps[8];
    int tid = threadIdx.x;
    float cnt = (float)hist[tid];
    float p = cnt * (1.0f / (float)NROW);
    float v = p * logf(p + 1e-7f);
    for (int o = 32; o; o >>= 1) v += __shfl_down(v, o);
    if ((tid & 63) == 0) ps[tid >> 6] = v;
    __syncthreads();
    if (tid == 0) {
        float s = 0.f;
#pragma unroll
        for (int w = 0; w < 8; ++w) s += ps[w];
        out[OUT_ELEMS]     = closs[0] * (1.0f / ((float)NROW * (float)D_));
        out[OUT_ELEMS + 1] = expf(-s);
    }
}

extern "C" void kernel_launch(void* const* d_in, const int* in_sizes, int n_in,
                              void* d_out, int out_size, void* d_ws, size_t ws_size,
                              hipStream_t stream) {
    const float* x  = (const float*)d_in[0];
    const float* cb = (const float*)d_in[1];
    float* out = (float*)d_out;
    float* ws  = (float*)d_ws;
    float* closs       = ws;                          // [0]
    unsigned int* hist = (unsigned int*)(ws + 1);     // [1..512]
    float* cbn2        = ws + 520;                    // [520..1031]

    zero_ws<<<1, 1024, 0, stream>>>(ws);
    cbnorm_k<<<128, 256, 0, stream>>>(cb, cbn2);
    vq_main<<<1024, THREADS, 0, stream>>>(x, cb, out, closs, hist, cbn2);
    finalize_k<<<1, 512, 0, stream>>>(hist, closs, out);
}

// Round 3
// 850.569 us; speedup vs baseline: 1.1924x; 1.1924x over previous
//
#include <hip/hip_runtime.h>
#include <cstdint>
#include <cfloat>

#define N_   32
#define D_   512
#define T_   2048
#define NC   512
#define NROW (N_ * T_)           // 65536 rows
#define OUT_ELEMS (N_ * D_ * T_) // 33554432
#define TB   128                 // t columns per block
#define THREADS 512
#define DELTA 2e-4f

typedef __attribute__((ext_vector_type(8))) short short8;
typedef __attribute__((ext_vector_type(4))) float f32x4;

// ws layout (floats): [0] closs | [16..527] hist u32[512] | [528..1039] cbn2
// | byte 4160: cbh short8[32768] (512KB) | cbl short8[32768] (512KB)

__device__ inline unsigned short f2bf(float x) {
    unsigned int u = __float_as_uint(x);
    return (unsigned short)((u + 0x7fffu + ((u >> 16) & 1u)) >> 16);
}
__device__ inline float bf2f(unsigned short b) {
    return __uint_as_float(((unsigned int)b) << 16);
}

__global__ void zero_ws(unsigned int* ws) {
    int i = threadIdx.x;
    if (i < 528) ws[i] = 0u;
}

__global__ __launch_bounds__(256) void cbnorm_k(const float* __restrict__ cb,
                                                float* __restrict__ cbn2) {
    int w = threadIdx.x >> 6, lane = threadIdx.x & 63;
    int c = blockIdx.x * 4 + w;
    const float4* row = (const float4*)(cb + (size_t)c * D_);
    float4 a = row[lane * 2], b = row[lane * 2 + 1];
    float s = a.x*a.x + a.y*a.y + a.z*a.z + a.w*a.w
            + b.x*b.x + b.y*b.y + b.z*b.z + b.w*b.w;
    for (int o = 32; o; o >>= 1) s += __shfl_down(s, o);
    if (lane == 0) cbn2[c] = s;
}

// codebook -> per-lane MFMA fragment order (hi/lo bf16 split)
__global__ __launch_bounds__(512) void cbfrag_k(const float* __restrict__ cb,
                                                short8* __restrict__ cbh,
                                                short8* __restrict__ cbl) {
    int tid = threadIdx.x;
    int l = tid & 63;
    int gw = blockIdx.x * 8 + (tid >> 6);    // 0..511
    int ks = gw >> 5, ct = gw & 31;
    const float* src = cb + (size_t)(ct * 16 + (l & 15)) * D_ + ks * 32 + 8 * (l >> 4);
    short8 h, lo;
#pragma unroll
    for (int j = 0; j < 8; ++j) {
        float v = src[j];
        unsigned short hb = f2bf(v);
        float hf = bf2f(hb);
        h[j]  = (short)hb;
        lo[j] = (short)f2bf(v - hf);
    }
    cbh[(ks * 32 + ct) * 64 + l] = h;
    cbl[(ks * 32 + ct) * 64 + l] = lo;
}

__global__ __launch_bounds__(THREADS, 2) void vq_main(
    const float* __restrict__ x, const float* __restrict__ cb,
    float* __restrict__ out, float* __restrict__ closs,
    unsigned int* __restrict__ hist, const float* __restrict__ cbn2g,
    const short8* __restrict__ cbh, const short8* __restrict__ cbl) {

    __shared__ unsigned int histl[NC];
    __shared__ int   ccnt[TB];
    __shared__ int   cand[TB][8];
    __shared__ int   sidx[TB];
    __shared__ float ot[64][TB + 1];

    const int tid = threadIdx.x;
    const int l = tid & 63, w = tid >> 6;
    const int g = l >> 4, li = l & 15;
    const int bid = blockIdx.x;
    const int n  = bid >> 4;
    const int t0 = (bid & 15) * TB;
    const int t  = t0 + w * 16 + li;
    const size_t xnb = (size_t)n * D_ * T_;

    histl[tid] = 0u;
    if (tid < TB) ccnt[tid] = 0;
    __syncthreads();

    f32x4 acc[32];
#pragma unroll
    for (int ct = 0; ct < 32; ++ct) acc[ct] = (f32x4){0.f, 0.f, 0.f, 0.f};

    float xsq = 0.f;
    const float* xcol = x + xnb + t;
    const short8* pah = cbh + l;
    const short8* pal = cbl + l;

    for (int ks = 0; ks < 16; ++ks) {
        float xv[8];
        const float* xp = xcol + (size_t)(ks * 32 + 8 * g) * T_;
#pragma unroll
        for (int j = 0; j < 8; ++j) xv[j] = xp[(size_t)j * T_];
        short8 bh, bl;
#pragma unroll
        for (int j = 0; j < 8; ++j) {
            xsq = fmaf(xv[j], xv[j], xsq);
            unsigned short hb = f2bf(xv[j]);
            float hf = bf2f(hb);
            bh[j] = (short)hb;
            bl[j] = (short)f2bf(xv[j] - hf);
        }
        const short8* pa = pah + ks * 2048;
        const short8* pl = pal + ks * 2048;
#pragma unroll
        for (int ct = 0; ct < 32; ++ct) {
            short8 a = pa[ct * 64];
            acc[ct] = __builtin_amdgcn_mfma_f32_16x16x32_bf16(a, bh, acc[ct], 0, 0, 0);
            acc[ct] = __builtin_amdgcn_mfma_f32_16x16x32_bf16(a, bl, acc[ct], 0, 0, 0);
        }
#pragma unroll
        for (int ct = 0; ct < 32; ++ct) {
            short8 a = pl[ct * 64];
            acc[ct] = __builtin_amdgcn_mfma_f32_16x16x32_bf16(a, bh, acc[ct], 0, 0, 0);
        }
    }

    // row norm (exact fp32 squares) across the 4 k-groups sharing this t
    xsq += __shfl_xor(xsq, 16);
    xsq += __shfl_xor(xsq, 32);
    float nrm = fmaxf(sqrtf(xsq), 1e-12f);
    float scl = 1.0f / nrm;
    float c1  = xsq * scl * scl;
    float n2s = -2.0f * scl;

    const float4* pcn = (const float4*)cbn2g;

    // per-lane argmin over its 128 codes (c ascending -> first-index tiebreak)
    float bv = FLT_MAX; int bi = 0;
#pragma unroll
    for (int ct = 0; ct < 32; ++ct) {
        float4 cn = pcn[ct * 4 + g];
        float cc[4] = {cn.x, cn.y, cn.z, cn.w};
#pragma unroll
        for (int r = 0; r < 4; ++r) {
            float dist = fmaf(n2s, acc[ct][r], c1 + cc[r]);
            int c = ct * 16 + g * 4 + r;
            if (dist < bv) { bv = dist; bi = c; }
        }
    }
    // butterfly combine across the 4 lane-groups (same t)
#pragma unroll
    for (int m = 16; m <= 32; m <<= 1) {
        float ov = __shfl_xor(bv, m);
        int   oi = __shfl_xor(bi, m);
        if (ov < bv || (ov == bv && oi < bi)) { bv = ov; bi = oi; }
    }

    // near-tie candidates within DELTA of the fp32 min
    float thr = bv + DELTA;
    int tl = w * 16 + li;
#pragma unroll
    for (int ct = 0; ct < 32; ++ct) {
        float4 cn = pcn[ct * 4 + g];
        float cc[4] = {cn.x, cn.y, cn.z, cn.w};
#pragma unroll
        for (int r = 0; r < 4; ++r) {
            float dist = fmaf(n2s, acc[ct][r], c1 + cc[r]);
            if (dist <= thr) {
                int pos = atomicAdd(&ccnt[tl], 1);
                if (pos < 8) cand[tl][pos] = ct * 16 + g * 4 + r;
            }
        }
    }

    // commit loss = sum of min distances (lanes l<16 hold one t each)
    float clp = (l < 16) ? bv : 0.f;
    clp += __shfl_down(clp, 8);
    clp += __shfl_down(clp, 4);
    clp += __shfl_down(clp, 2);
    clp += __shfl_down(clp, 1);
    if (l == 0) atomicAdd(closs, clp);
    __syncthreads();

    // fp64 refinement for ambiguous rows; block-local histogram
    if (tid < TB) {
        int cnt = ccnt[tid];
        int bc = cand[tid][0];
        if (cnt > 1) {
            int m = cnt < 8 ? cnt : 8;
            const float* xr = x + xnb + t0 + tid;
            double xn2d = 0.0;
            for (int d = 0; d < D_; ++d) { double v = (double)xr[(size_t)d * T_]; xn2d += v * v; }
            double nr = sqrt(xn2d); if (nr < 1e-12) nr = 1e-12;
            double inv = 1.0 / nr;
            double bd = 1e300; bc = 1 << 30;
            for (int k = 0; k < m; ++k) {
                int c = cand[tid][k];
                const float* cr = cb + (size_t)c * D_;
                double s = 0.0;
                for (int d = 0; d < D_; ++d) {
                    double df = (double)xr[(size_t)d * T_] * inv - (double)cr[d];
                    s += df * df;
                }
                if (s < bd || (s == bd && c < bc)) { bd = s; bc = c; }
            }
        }
        sidx[tid] = bc;
        atomicAdd(&histl[bc], 1u);
    }
    __syncthreads();
    if (histl[tid]) atomicAdd(&hist[tid], histl[tid]);

    // epilogue: gather chosen codebook rows via LDS transpose, coalesced out write
    const int tt = tid >> 2, seg = tid & 3;
    for (int ds = 0; ds < 8; ++ds) {
        int dbase = ds * 64;
        {
            int c = sidx[tt];
            const float4* src = (const float4*)(cb + (size_t)c * D_ + dbase + seg * 16);
#pragma unroll
            for (int q = 0; q < 4; ++q) {
                float4 v = src[q];
                int dd = seg * 16 + q * 4;
                ot[dd + 0][tt] = v.x; ot[dd + 1][tt] = v.y;
                ot[dd + 2][tt] = v.z; ot[dd + 3][tt] = v.w;
            }
        }
        __syncthreads();
        {
            int dd0 = tid >> 7;         // 0..3
            int tc  = tid & 127;
#pragma unroll
            for (int p = 0; p < 16; ++p) {
                int dd = p * 4 + dd0;
                out[xnb + (size_t)(dbase + dd) * T_ + t0 + tc] = ot[dd][tc];
            }
        }
        __syncthreads();
    }
}

__global__ __launch_bounds__(512) void finalize_k(const unsigned int* __restrict__ hist,
                                                  const float* __restrict__ closs,
                                                  float* __restrict__ out) {
    __shared__ float ps[8];
    int tid = threadIdx.x;
    float cnt = (float)hist[tid];
    float p = cnt * (1.0f / (float)NROW);
    float v = p * logf(p + 1e-7f);
    for (int o = 32; o; o >>= 1) v += __shfl_down(v, o);
    if ((tid & 63) == 0) ps[tid >> 6] = v;
    __syncthreads();
    if (tid == 0) {
        float s = 0.f;
#pragma unroll
        for (int w = 0; w < 8; ++w) s += ps[w];
        out[OUT_ELEMS]     = closs[0] * (1.0f / ((float)NROW * (float)D_));
        out[OUT_ELEMS + 1] = expf(-s);
    }
}

extern "C" void kernel_launch(void* const* d_in, const int* in_sizes, int n_in,
                              void* d_out, int out_size, void* d_ws, size_t ws_size,
                              hipStream_t stream) {
    const float* x  = (const float*)d_in[0];
    const float* cb = (const float*)d_in[1];
    float* out = (float*)d_out;
    float* ws  = (float*)d_ws;
    float* closs       = ws;                              // [0]
    unsigned int* hist = (unsigned int*)(ws + 16);        // [16..527]
    float* cbn2        = ws + 528;                        // [528..1039]
    short8* cbh        = (short8*)(ws + 1040);            // 512 KB
    short8* cbl        = cbh + 16 * 32 * 64;              // 512 KB

    zero_ws<<<1, 1024, 0, stream>>>((unsigned int*)ws);
    cbnorm_k<<<128, 256, 0, stream>>>(cb, cbn2);
    cbfrag_k<<<64, 512, 0, stream>>>(cb, cbh, cbl);
    vq_main<<<512, THREADS, 0, stream>>>(x, cb, out, closs, hist, cbn2, cbh, cbl);
    finalize_k<<<1, 512, 0, stream>>>(hist, closs, out);
}

// Round 4
// 458.956 us; speedup vs baseline: 2.2099x; 1.8533x over previous
//
#include <hip/hip_runtime.h>
#include <cstdint>
#include <cfloat>

#define N_   32
#define D_   512
#define T_   2048
#define NC   512
#define NROW (N_ * T_)           // 65536 rows
#define OUT_ELEMS (N_ * D_ * T_) // 33554432
#define TB   128                 // t columns per block
#define THREADS 512
#define DELTA 2e-4f

typedef __attribute__((ext_vector_type(8))) short short8;
typedef __attribute__((ext_vector_type(4))) float f32x4;

// ws layout (floats): [0] closs | [16..527] hist u32[512] | [528..1039] cbn2
// | byte 4160: cbh short8[32768] (512KB) | cbl short8[32768] (512KB)

__device__ inline unsigned short f2bf(float x) {
    unsigned int u = __float_as_uint(x);
    return (unsigned short)((u + 0x7fffu + ((u >> 16) & 1u)) >> 16);
}
__device__ inline float bf2f(unsigned short b) {
    return __uint_as_float(((unsigned int)b) << 16);
}

__global__ void zero_ws(unsigned int* ws) {
    int i = threadIdx.x;
    if (i < 528) ws[i] = 0u;
}

__global__ __launch_bounds__(256) void cbnorm_k(const float* __restrict__ cb,
                                                float* __restrict__ cbn2) {
    int w = threadIdx.x >> 6, lane = threadIdx.x & 63;
    int c = blockIdx.x * 4 + w;
    const float4* row = (const float4*)(cb + (size_t)c * D_);
    float4 a = row[lane * 2], b = row[lane * 2 + 1];
    float s = a.x*a.x + a.y*a.y + a.z*a.z + a.w*a.w
            + b.x*b.x + b.y*b.y + b.z*b.z + b.w*b.w;
    for (int o = 32; o; o >>= 1) s += __shfl_down(s, o);
    if (lane == 0) cbn2[c] = s;
}

// codebook -> per-lane MFMA fragment order (hi/lo bf16 split)
__global__ __launch_bounds__(512) void cbfrag_k(const float* __restrict__ cb,
                                                short8* __restrict__ cbh,
                                                short8* __restrict__ cbl) {
    int tid = threadIdx.x;
    int l = tid & 63;
    int gw = blockIdx.x * 8 + (tid >> 6);    // 0..511
    int ks = gw >> 5, ct = gw & 31;
    const float* src = cb + (size_t)(ct * 16 + (l & 15)) * D_ + ks * 32 + 8 * (l >> 4);
    short8 h, lo;
#pragma unroll
    for (int j = 0; j < 8; ++j) {
        float v = src[j];
        unsigned short hb = f2bf(v);
        float hf = bf2f(hb);
        h[j]  = (short)hb;
        lo[j] = (short)f2bf(v - hf);
    }
    cbh[(ks * 32 + ct) * 64 + l] = h;
    cbl[(ks * 32 + ct) * 64 + l] = lo;
}

__global__ __launch_bounds__(THREADS, 2) void vq_main(
    const float* __restrict__ x, const float* __restrict__ cb,
    float* __restrict__ out, float* __restrict__ closs,
    unsigned int* __restrict__ hist, const float* __restrict__ cbn2g,
    const short8* __restrict__ cbh, const short8* __restrict__ cbl) {

    __shared__ union U {
        struct { short8 fh[32][64]; short8 fl[32][64]; } kl;   // 64 KB frag slab
        struct { float ot[64][TB + 4]; } ep;                   // epilogue transpose
    } u;
    __shared__ unsigned int histl[NC];
    __shared__ int   ccnt[TB];
    __shared__ int   cand[TB][8];
    __shared__ int   sidx[TB];
    __shared__ int   qrow[TB];
    __shared__ int   qn;

    const int tid = threadIdx.x;
    const int l = tid & 63, w = tid >> 6;
    const int g = l >> 4, li = l & 15;
    const int bid = blockIdx.x;
    const int n  = bid >> 4;
    const int t0 = (bid & 15) * TB;
    const int t  = t0 + w * 16 + li;
    const size_t xnb = (size_t)n * D_ * T_;

    histl[tid] = 0u;
    if (tid < TB) ccnt[tid] = 0;
    if (tid == 0) qn = 0;

    f32x4 acc[32];
#pragma unroll
    for (int ct = 0; ct < 32; ++ct) acc[ct] = (f32x4){0.f, 0.f, 0.f, 0.f};

    float xsq = 0.f;
    const float* xcol = x + xnb + t;
    short8* fh_flat = (short8*)u.kl.fh;
    short8* fl_flat = (short8*)u.kl.fl;

    for (int ks = 0; ks < 16; ++ks) {
        __syncthreads();            // prior iter's LDS reads done
        // stage 64KB fragment slab for this k-step (per-block, not per-wave)
        const short8* sh = cbh + ks * 2048;
        const short8* sl = cbl + ks * 2048;
#pragma unroll
        for (int i = 0; i < 4; ++i) fh_flat[i * 512 + tid] = sh[i * 512 + tid];
#pragma unroll
        for (int i = 0; i < 4; ++i) fl_flat[i * 512 + tid] = sl[i * 512 + tid];

        // x column loads + bf16 hi/lo split (independent of LDS, overlaps staging)
        float xv[8];
        const float* xp = xcol + (size_t)(ks * 32 + 8 * g) * T_;
#pragma unroll
        for (int j = 0; j < 8; ++j) xv[j] = xp[(size_t)j * T_];
        short8 bh, bl;
#pragma unroll
        for (int j = 0; j < 8; ++j) {
            xsq = fmaf(xv[j], xv[j], xsq);
            unsigned short hb = f2bf(xv[j]);
            float hf = bf2f(hb);
            bh[j] = (short)hb;
            bl[j] = (short)f2bf(xv[j] - hf);
        }
        __syncthreads();            // slab ready
#pragma unroll
        for (int ct = 0; ct < 32; ++ct) {
            short8 a = u.kl.fh[ct][l];
            acc[ct] = __builtin_amdgcn_mfma_f32_16x16x32_bf16(a, bh, acc[ct], 0, 0, 0);
            acc[ct] = __builtin_amdgcn_mfma_f32_16x16x32_bf16(a, bl, acc[ct], 0, 0, 0);
        }
#pragma unroll
        for (int ct = 0; ct < 32; ++ct) {
            short8 a = u.kl.fl[ct][l];
            acc[ct] = __builtin_amdgcn_mfma_f32_16x16x32_bf16(a, bh, acc[ct], 0, 0, 0);
        }
    }

    // row norm (exact fp32 squares) across the 4 k-groups sharing this t
    xsq += __shfl_xor(xsq, 16);
    xsq += __shfl_xor(xsq, 32);
    float nrm = fmaxf(sqrtf(xsq), 1e-12f);
    float scl = 1.0f / nrm;
    float c1  = xsq * scl * scl;
    float n2s = -2.0f * scl;

    const float4* pcn = (const float4*)cbn2g;

    // per-lane argmin over its 128 codes (c ascending -> first-index tiebreak)
    float bv = FLT_MAX; int bi = 0;
#pragma unroll
    for (int ct = 0; ct < 32; ++ct) {
        float4 cn = pcn[ct * 4 + g];
        float cc[4] = {cn.x, cn.y, cn.z, cn.w};
#pragma unroll
        for (int r = 0; r < 4; ++r) {
            float dist = fmaf(n2s, acc[ct][r], c1 + cc[r]);
            int c = ct * 16 + g * 4 + r;
            if (dist < bv) { bv = dist; bi = c; }
        }
    }
    // butterfly combine across the 4 lane-groups (same t)
#pragma unroll
    for (int m = 16; m <= 32; m <<= 1) {
        float ov = __shfl_xor(bv, m);
        int   oi = __shfl_xor(bi, m);
        if (ov < bv || (ov == bv && oi < bi)) { bv = ov; bi = oi; }
    }

    // near-tie candidates within DELTA of the fp32 min
    float thr = bv + DELTA;
    int tl = w * 16 + li;
#pragma unroll
    for (int ct = 0; ct < 32; ++ct) {
        float4 cn = pcn[ct * 4 + g];
        float cc[4] = {cn.x, cn.y, cn.z, cn.w};
#pragma unroll
        for (int r = 0; r < 4; ++r) {
            float dist = fmaf(n2s, acc[ct][r], c1 + cc[r]);
            if (dist <= thr) {
                int pos = atomicAdd(&ccnt[tl], 1);
                if (pos < 8) cand[tl][pos] = ct * 16 + g * 4 + r;
            }
        }
    }

    // commit loss = sum of min distances (lanes l<16 hold one t each)
    float clp = (l < 16) ? bv : 0.f;
    clp += __shfl_down(clp, 8);
    clp += __shfl_down(clp, 4);
    clp += __shfl_down(clp, 2);
    clp += __shfl_down(clp, 1);
    if (l == 0) atomicAdd(closs, clp);
    __syncthreads();

    // build refine queue; default choice = sole candidate
    if (tid < TB) {
        sidx[tid] = cand[tid][0];
        if (ccnt[tid] > 1) { int p = atomicAdd(&qn, 1); qrow[p] = tid; }
    }
    __syncthreads();

    // wave-parallel fp64 refinement (lane l owns d = l, l+64, ..., l+448)
    int nq = qn;
    for (int q = w; q < nq; q += 8) {
        int row = qrow[q];
        const float* xr = x + xnb + t0 + row;
        float xv8[8];
        double xs = 0.0;
#pragma unroll
        for (int k2 = 0; k2 < 8; ++k2) {
            float v = xr[(size_t)(l + 64 * k2) * T_];
            xv8[k2] = v;
            xs += (double)v * (double)v;
        }
#pragma unroll
        for (int o = 32; o; o >>= 1) xs += __shfl_xor(xs, o);
        if (xs < 1e-24) xs = 1e-24;
        double inv = 1.0 / sqrt(xs);
        double bd = 1e300; int bc = 1 << 30;
        int m = ccnt[row] < 8 ? ccnt[row] : 8;
        for (int kk = 0; kk < m; ++kk) {
            int c = cand[row][kk];
            const float* cr = cb + (size_t)c * D_;
            double s = 0.0;
#pragma unroll
            for (int k2 = 0; k2 < 8; ++k2) {
                double df = (double)xv8[k2] * inv - (double)cr[l + 64 * k2];
                s += df * df;
            }
#pragma unroll
            for (int o = 32; o; o >>= 1) s += __shfl_xor(s, o);
            if (s < bd || (s == bd && c < bc)) { bd = s; bc = c; }
        }
        if (l == 0) sidx[row] = bc;
    }
    __syncthreads();

    if (tid < TB) atomicAdd(&histl[sidx[tid]], 1u);
    __syncthreads();
    if (histl[tid]) atomicAdd(&hist[tid], histl[tid]);

    // epilogue: gather chosen codebook rows via LDS transpose, float4 out writes
    const int tt = tid >> 2, seg = tid & 3;
    const int dd0 = tid >> 5;       // 0..15
    const int tc4 = tid & 31;       // 0..31 (4 t each)
    for (int ds = 0; ds < 8; ++ds) {
        int dbase = ds * 64;
        {
            int c = sidx[tt];
            const float4* src = (const float4*)(cb + (size_t)c * D_ + dbase + seg * 16);
#pragma unroll
            for (int q = 0; q < 4; ++q) {
                float4 v = src[q];
                int dd = seg * 16 + q * 4;
                u.ep.ot[dd + 0][tt] = v.x; u.ep.ot[dd + 1][tt] = v.y;
                u.ep.ot[dd + 2][tt] = v.z; u.ep.ot[dd + 3][tt] = v.w;
            }
        }
        __syncthreads();
#pragma unroll
        for (int p = 0; p < 4; ++p) {
            int dd = p * 16 + dd0;
            float4 v = *(const float4*)&u.ep.ot[dd][tc4 * 4];
            *(float4*)&out[xnb + (size_t)(dbase + dd) * T_ + t0 + tc4 * 4] = v;
        }
        __syncthreads();
    }
}

__global__ __launch_bounds__(512) void finalize_k(const unsigned int* __restrict__ hist,
                                                  const float* __restrict__ closs,
                                                  float* __restrict__ out) {
    __shared__ float ps[8];
    int tid = threadIdx.x;
    float cnt = (float)hist[tid];
    float p = cnt * (1.0f / (float)NROW);
    float v = p * logf(p + 1e-7f);
    for (int o = 32; o; o >>= 1) v += __shfl_down(v, o);
    if ((tid & 63) == 0) ps[tid >> 6] = v;
    __syncthreads();
    if (tid == 0) {
        float s = 0.f;
#pragma unroll
        for (int w = 0; w < 8; ++w) s += ps[w];
        out[OUT_ELEMS]     = closs[0] * (1.0f / ((float)NROW * (float)D_));
        out[OUT_ELEMS + 1] = expf(-s);
    }
}

extern "C" void kernel_launch(void* const* d_in, const int* in_sizes, int n_in,
                              void* d_out, int out_size, void* d_ws, size_t ws_size,
                              hipStream_t stream) {
    const float* x  = (const float*)d_in[0];
    const float* cb = (const float*)d_in[1];
    float* out = (float*)d_out;
    float* ws  = (float*)d_ws;
    float* closs       = ws;                              // [0]
    unsigned int* hist = (unsigned int*)(ws + 16);        // [16..527]
    float* cbn2        = ws + 528;                        // [528..1039]
    short8* cbh        = (short8*)(ws + 1040);            // 512 KB
    short8* cbl        = cbh + 16 * 32 * 64;              // 512 KB

    zero_ws<<<1, 1024, 0, stream>>>((unsigned int*)ws);
    cbnorm_k<<<128, 256, 0, stream>>>(cb, cbn2);
    cbfrag_k<<<64, 512, 0, stream>>>(cb, cbh, cbl);
    vq_main<<<512, THREADS, 0, stream>>>(x, cb, out, closs, hist, cbn2, cbh, cbl);
    finalize_k<<<1, 512, 0, stream>>>(hist, closs, out);
}